// Round 16
// baseline (245.727 us; speedup 1.0000x reference)
//
#include <hip/hip_runtime.h>
#include <math.h>

#define B_TOK 2048
#define DMODEL 1024
#define HDIM 4096
#define NEXP 8
#define TOPK 2

#define BM 128
#define BK 64
#define MAX_TILES 40
#define MAX_T256 24
#define NG1 768  // MAX_T256 * (HDIM/128); divisible by 8

typedef __attribute__((ext_vector_type(8))) short bf16x8;
typedef __attribute__((ext_vector_type(4))) float f32x4;

__device__ __forceinline__ unsigned short f2b(float f) {
  unsigned u = __builtin_bit_cast(unsigned, f);
  unsigned r = (u + 0x7FFFu + ((u >> 16) & 1u)) >> 16;
  return (unsigned short)r;
}

__device__ __forceinline__ void load_lds16(const void* g, void* l) {
  __builtin_amdgcn_global_load_lds(
      (const __attribute__((address_space(1))) unsigned int*)g,
      (__attribute__((address_space(3))) unsigned int*)l, 16, 0, 0);
}

// exact-gelu via branchless A&S 7.1.26 erf (|err| <= 1.5e-7, << bf16 ulp)
__device__ __forceinline__ float gelu_fast(float v) {
  float x = v * 0.70710678118654752f;
  float ax = fabsf(x);
  float t = 1.0f / (1.0f + 0.3275911f * ax);
  float e = exp2f(-ax * ax * 1.4426950408889634f);
  float p = t * (0.254829592f +
                 t * (-0.284496736f +
                      t * (1.421413741f +
                           t * (-1.453152027f + t * 1.061405429f))));
  float er = 1.0f - p * e;
  er = copysignf(er, x);
  return 0.5f * v * (1.0f + er);
}

// ---- fused [gate | conv1]: blocks 0..511 gate (+x16 convert, +out zero),
// ---- blocks 512.. conv1 (w1 [E][D][H] f32 -> Wt1 [E][H][D] bf16).
__global__ __launch_bounds__(256) void gate_conv_kernel(
    const float* __restrict__ x, const float* __restrict__ gw,
    const float* __restrict__ gb, int* __restrict__ idx2,
    float* __restrict__ sc2, float* __restrict__ out,
    unsigned short* __restrict__ x16, const float* __restrict__ W,
    unsigned short* __restrict__ Wt) {
  __shared__ unsigned L[64 * 33];
  if (blockIdx.x < 512) {
    int lane = threadIdx.x & 63;
    int w = threadIdx.x >> 6;
    int b = blockIdx.x * 4 + w;
    {
      float4 z = make_float4(0.f, 0.f, 0.f, 0.f);
      float* orow = out + (size_t)(blockIdx.x * 4) * DMODEL;
#pragma unroll
      for (int i = 0; i < 4; ++i)
        *(float4*)(orow + i * 1024 + threadIdx.x * 4) = z;
    }
    double acc[NEXP];
#pragma unroll
    for (int e = 0; e < NEXP; ++e) acc[e] = 0.0;
    const float* xr = x + (size_t)b * DMODEL;
#pragma unroll
    for (int i = 0; i < 4; ++i) {
      float4 xv = *(const float4*)(xr + i * 256 + lane * 4);
      ushort4 o = make_ushort4(f2b(xv.x), f2b(xv.y), f2b(xv.z), f2b(xv.w));
      *(ushort4*)(x16 + (size_t)b * DMODEL + i * 256 + lane * 4) = o;
#pragma unroll
      for (int e = 0; e < NEXP; ++e) {
        float4 wv = *(const float4*)(gw + e * DMODEL + i * 256 + lane * 4);
        acc[e] += (double)xv.x * wv.x + (double)xv.y * wv.y +
                  (double)xv.z * wv.z + (double)xv.w * wv.w;
      }
    }
#pragma unroll
    for (int e = 0; e < NEXP; ++e) {
      double v = acc[e];
      for (int o = 1; o < 64; o <<= 1) v += __shfl_xor(v, o, 64);
      acc[e] = v + (double)gb[e];
    }
    if (lane == 0) {
      int i0 = 0;
      double v0 = acc[0];
#pragma unroll
      for (int e = 1; e < NEXP; ++e)
        if (acc[e] > v0) { v0 = acc[e]; i0 = e; }
      int i1 = -1;
      double v1 = -1e300;
#pragma unroll
      for (int e = 0; e < NEXP; ++e)
        if (e != i0 && acc[e] > v1) { v1 = acc[e]; i1 = e; }
      double t = exp(v1 - v0);
      float s0 = (float)(1.0 / (1.0 + t));
      float s1 = (float)(t / (1.0 + t));
      idx2[b * 2] = i0;
      idx2[b * 2 + 1] = i1;
      sc2[b * 2] = s0;
      sc2[b * 2 + 1] = s1;
    }
  } else {
    int bid0 = blockIdx.x - 512;
    int bidx = (bid0 & 7) * 1024 + (bid0 >> 3);
    int nt = bidx % (HDIM / 64);
    int r2 = bidx / (HDIM / 64);
    int kt = r2 % (DMODEL / 64);
    int e = r2 / (DMODEL / 64);
    int tid = threadIdx.x;

    const float* src =
        W + (long)e * DMODEL * HDIM + (long)(kt * 64) * HDIM + nt * 64;
    int kp = tid >> 3;
    int nb = tid & 7;
    const float* r0 = src + (long)(2 * kp) * HDIM + nb * 8;
    const float* r1 = r0 + HDIM;
    float4 va0 = *(const float4*)r0;
    float4 va1 = *(const float4*)(r0 + 4);
    float4 vb0 = *(const float4*)r1;
    float4 vb1 = *(const float4*)(r1 + 4);
    const float* a = (const float*)&va0;
    const float* bq = (const float*)&vb0;
#pragma unroll
    for (int j = 0; j < 4; ++j) {
      unsigned p = (unsigned)f2b(a[j]) | ((unsigned)f2b(bq[j]) << 16);
      L[(nb * 8 + j) * 33 + kp] = p;
    }
    const float* a2 = (const float*)&va1;
    const float* b2 = (const float*)&vb1;
#pragma unroll
    for (int j = 0; j < 4; ++j) {
      unsigned p = (unsigned)f2b(a2[j]) | ((unsigned)f2b(b2[j]) << 16);
      L[(nb * 8 + 4 + j) * 33 + kp] = p;
    }
    __syncthreads();
    int n = tid >> 2;
    int part = tid & 3;
    unsigned q[8];
#pragma unroll
    for (int j = 0; j < 8; ++j) q[j] = L[n * 33 + part * 8 + j];
    unsigned* dst = (unsigned*)(Wt + (long)e * HDIM * DMODEL +
                                (long)(nt * 64 + n) * DMODEL + kt * 64) +
                    part * 8;
    *(uint4*)dst = make_uint4(q[0], q[1], q[2], q[3]);
    *(uint4*)(dst + 4) = make_uint4(q[4], q[5], q[6], q[7]);
  }
}

// ---- route: single block; histogram + stable counting sort + BOTH tile maps ----
__global__ __launch_bounds__(256) void route_kernel(
    const int* __restrict__ idx2, const float* __restrict__ sc2,
    int* __restrict__ tile_map, int* __restrict__ ntiles,
    int* __restrict__ tm256, int* __restrict__ nt256,
    int* __restrict__ pos_of, int* __restrict__ row_of,
    float* __restrict__ s_of) {
  __shared__ int lc[NEXP][257];
  __shared__ int offs[NEXP + 1];
  const int tid = threadIdx.x;
  const int base = tid * 16;
  row_of[4096 + tid] = 0;  // tail guard for G1's indirect staging
#pragma unroll
  for (int e = 0; e < NEXP; ++e) lc[e][tid + 1] = 0;
  if (tid < NEXP) lc[tid][0] = 0;
  __syncthreads();
  int loc[16];
#pragma unroll
  for (int j = 0; j < 16; ++j) {
    int e = idx2[base + j];
    loc[j] = e;
    atomicAdd(&lc[e][tid + 1], 1);
  }
  __syncthreads();
  if (tid < NEXP) {
    int s = 0;
    for (int i = 1; i <= 256; ++i) {
      s += lc[tid][i];
      lc[tid][i] = s;
    }
  }
  __syncthreads();
  if (tid == 0) {
    offs[0] = 0;
    for (int e = 0; e < NEXP; ++e) offs[e + 1] = offs[e] + lc[e][256];
    int tt = 0, t2 = 0;
    for (int e = 0; e < NEXP; ++e) {
      int cnt = lc[e][256];
      int bse = offs[e];
      for (int t = 0; t * BM < cnt; ++t) {
        tile_map[tt * 4 + 0] = e;
        tile_map[tt * 4 + 1] = bse + t * BM;
        tile_map[tt * 4 + 2] = (cnt - t * BM) < BM ? (cnt - t * BM) : BM;
        tile_map[tt * 4 + 3] = 0;
        ++tt;
      }
      for (int t = 0; t * 256 < cnt; ++t) {
        tm256[t2 * 4 + 0] = e;
        tm256[t2 * 4 + 1] = bse + t * 256;
        tm256[t2 * 4 + 2] = (cnt - t * 256) < 256 ? (cnt - t * 256) : 256;
        tm256[t2 * 4 + 3] = 0;
        ++t2;
      }
    }
    *ntiles = tt;
    *nt256 = t2;
  }
  __syncthreads();
#pragma unroll
  for (int e = 0; e < NEXP; ++e) lc[e][tid] += offs[e];
  __syncthreads();
#pragma unroll
  for (int j = 0; j < 16; ++j) {
    int e = loc[j];
    int p = lc[e][tid];
    lc[e][tid] = p + 1;
    int t = base + j;
    pos_of[t] = p;
    row_of[p] = t >> 1;
    s_of[p] = sc2[t];
  }
}

// ---- standalone conv2 (fallback path): W[e][k][n] f32 -> Wt[e][n][k] bf16 ----
__global__ __launch_bounds__(256) void convT_kernel(
    const float* __restrict__ W, unsigned short* __restrict__ Wt, int Kd, int Nd,
    int tilesN, int cpx) {
  __shared__ unsigned L[64 * 33];
  int bidx = (blockIdx.x & 7) * cpx + (blockIdx.x >> 3);
  int nt = bidx % tilesN;
  int r2 = bidx / tilesN;
  int tilesK = Kd >> 6;
  int kt = r2 % tilesK;
  int e = r2 / tilesK;
  int tid = threadIdx.x;

  const float* src = W + (long)e * Kd * Nd + (long)(kt * 64) * Nd + nt * 64;
  int kp = tid >> 3;
  int nb = tid & 7;
  const float* r0 = src + (long)(2 * kp) * Nd + nb * 8;
  const float* r1 = r0 + Nd;
  float4 va0 = *(const float4*)r0;
  float4 va1 = *(const float4*)(r0 + 4);
  float4 vb0 = *(const float4*)r1;
  float4 vb1 = *(const float4*)(r1 + 4);
  const float* a = (const float*)&va0;
  const float* bq = (const float*)&vb0;
#pragma unroll
  for (int j = 0; j < 4; ++j) {
    unsigned p = (unsigned)f2b(a[j]) | ((unsigned)f2b(bq[j]) << 16);
    L[(nb * 8 + j) * 33 + kp] = p;
  }
  const float* a2 = (const float*)&va1;
  const float* b2 = (const float*)&vb1;
#pragma unroll
  for (int j = 0; j < 4; ++j) {
    unsigned p = (unsigned)f2b(a2[j]) | ((unsigned)f2b(b2[j]) << 16);
    L[(nb * 8 + 4 + j) * 33 + kp] = p;
  }
  __syncthreads();
  int n = tid >> 2;
  int part = tid & 3;
  unsigned q[8];
#pragma unroll
  for (int j = 0; j < 8; ++j) q[j] = L[n * 33 + part * 8 + j];
  unsigned* dst = (unsigned*)(Wt + (long)e * Nd * Kd + (long)(nt * 64 + n) * Kd +
                              kt * 64) +
                  part * 8;
  *(uint4*)dst = make_uint4(q[0], q[1], q[2], q[3]);
  *(uint4*)(dst + 4) = make_uint4(q[4], q[5], q[6], q[7]);
}

// ---- fused [G1 | conv2]: blocks <NG1 = G1 (256x128, 512 thr, proven body);
// ---- blocks >=NG1 = conv2 (w2 f32 -> Wt2 bf16), 2 tiles per 512-thr block.
__global__ __launch_bounds__(512) void g1conv2_kernel(
    const unsigned short* __restrict__ x16, const int* __restrict__ row_of,
    const unsigned short* __restrict__ Bt, const float* __restrict__ bias,
    unsigned short* __restrict__ Cout, const int* __restrict__ tm256,
    const int* __restrict__ nt256, const float* __restrict__ W2,
    unsigned short* __restrict__ Wt2) {
  __shared__ __align__(16) char SM[49152];
  if (blockIdx.x < NG1) {
    const int K = DMODEL, N = HDIM;
    const int nb = N / 128;
    const int tile = blockIdx.x / nb;
    if (tile >= *nt256) return;
    const int ct = blockIdx.x % nb;
    const int e = tm256[tile * 4 + 0];
    const int row0 = tm256[tile * 4 + 1];
    const int rows = tm256[tile * 4 + 2];
    const int n0 = ct * 128;
    const unsigned short* B_e = Bt + (long)e * (long)N * K + (long)n0 * K;

    unsigned short* Asm = (unsigned short*)SM;            // 256*64
    unsigned short* Bsm = (unsigned short*)SM + 256 * BK; // 128*64

    const int tid = threadIdx.x;
    const int lane = tid & 63;
    const int w = tid >> 6;
    const int wr = (w >> 1) * 64;
    const int wc = (w & 1) * 64;
    const int l15 = lane & 15;
    const int l4 = lane >> 4;

    int gr[4];
#pragma unroll
    for (int it = 0; it < 4; ++it) gr[it] = row_of[row0 + it * 64 + (tid >> 3)];
    const int kcsA = (tid & 7) ^ ((tid >> 3) & 7);

    f32x4 acc[4][4] = {};

    for (int k0 = 0; k0 < K; k0 += BK) {
#pragma unroll
      for (int it = 0; it < 4; ++it) {
        load_lds16(x16 + (size_t)gr[it] * K + k0 + kcsA * 8,
                   ((char*)Asm) + (size_t)(it * 512 + w * 64) * 16);
      }
#pragma unroll
      for (int it = 0; it < 2; ++it) {
        int c = it * 512 + tid;
        int r = c >> 3, kc = c & 7;
        int kcs = kc ^ (r & 7);
        load_lds16(B_e + (size_t)r * K + k0 + kcs * 8,
                   ((char*)Bsm) + (size_t)(it * 512 + w * 64) * 16);
      }
      __syncthreads();
#pragma unroll
      for (int kk = 0; kk < 2; ++kk) {
        bf16x8 a[4], b[4];
#pragma unroll
        for (int m = 0; m < 4; ++m) {
          int row = wr + m * 16 + l15;
          int ch = (kk * 4 + l4) ^ (l15 & 7);
          a[m] = *(const bf16x8*)&Asm[row * BK + ch * 8];
        }
#pragma unroll
        for (int n = 0; n < 4; ++n) {
          int row = wc + n * 16 + l15;
          int ch = (kk * 4 + l4) ^ (l15 & 7);
          b[n] = *(const bf16x8*)&Bsm[row * BK + ch * 8];
        }
#pragma unroll
        for (int m = 0; m < 4; ++m)
#pragma unroll
          for (int n = 0; n < 4; ++n)
            acc[m][n] = __builtin_amdgcn_mfma_f32_16x16x32_bf16(a[m], b[n],
                                                                acc[m][n], 0, 0, 0);
      }
      __syncthreads();
    }

    const float* bias_e = bias + (long)e * HDIM;
#pragma unroll
    for (int m = 0; m < 4; ++m) {
#pragma unroll
      for (int i = 0; i < 4; ++i) {
        int r = wr + m * 16 + l4 * 4 + i;
        if (r < rows) {
          size_t grow = (size_t)(row0 + r) * HDIM;
#pragma unroll
          for (int n = 0; n < 4; ++n) {
            int cg = n0 + wc + n * 16 + l15;
            float v = acc[m][n][i] + bias_e[cg];
            v = gelu_fast(v);
            Cout[grow + cg] = f2b(v);
          }
        }
      }
    }
  } else {
    // conv2: 2 tiles per block. Kd=4096, Nd=1024, tilesN=16, 8192 tiles total.
    int lb = blockIdx.x - NG1;  // 0..4095
    int half = threadIdx.x >> 8;
    int tid = threadIdx.x & 255;
    int v = (lb & 7) * 1024 + (lb >> 3) + half * 512;  // XCD-chunked, bijective
    int nt = v % (DMODEL / 64);
    int r2 = v / (DMODEL / 64);
    int kt = r2 % (HDIM / 64);
    int e = r2 / (HDIM / 64);

    unsigned* L = (unsigned*)SM + half * 2112;  // 64*33 words per half

    const float* src =
        W2 + (long)e * HDIM * DMODEL + (long)(kt * 64) * DMODEL + nt * 64;
    int kp = tid >> 3;
    int nb = tid & 7;
    const float* r0 = src + (long)(2 * kp) * DMODEL + nb * 8;
    const float* r1 = r0 + DMODEL;
    float4 va0 = *(const float4*)r0;
    float4 va1 = *(const float4*)(r0 + 4);
    float4 vb0 = *(const float4*)r1;
    float4 vb1 = *(const float4*)(r1 + 4);
    const float* a = (const float*)&va0;
    const float* bq = (const float*)&vb0;
#pragma unroll
    for (int j = 0; j < 4; ++j) {
      unsigned p = (unsigned)f2b(a[j]) | ((unsigned)f2b(bq[j]) << 16);
      L[(nb * 8 + j) * 33 + kp] = p;
    }
    const float* a2 = (const float*)&va1;
    const float* b2 = (const float*)&vb1;
#pragma unroll
    for (int j = 0; j < 4; ++j) {
      unsigned p = (unsigned)f2b(a2[j]) | ((unsigned)f2b(b2[j]) << 16);
      L[(nb * 8 + 4 + j) * 33 + kp] = p;
    }
    __syncthreads();
    int n = tid >> 2;
    int part = tid & 3;
    unsigned q[8];
#pragma unroll
    for (int j = 0; j < 8; ++j) q[j] = L[n * 33 + part * 8 + j];
    unsigned* dst = (unsigned*)(Wt2 + (long)e * DMODEL * HDIM +
                                (long)(nt * 64 + n) * HDIM + kt * 64) +
                    part * 8;
    *(uint4*)dst = make_uint4(q[0], q[1], q[2], q[3]);
    *(uint4*)(dst + 4) = make_uint4(q[4], q[5], q[6], q[7]);
  }
}

// ------- G2: 128x64, double-buffered + counted vmcnt, XCD-chunked tile map ----
// Grid = 8 XCDs x 80 slots (lt=slot>>4 local tile, ct=slot&15). Each XCD owns a
// contiguous tile chunk (bijective q/r split); the 16 ct-instances of an A-tile
// run back-to-back on one XCD -> A-tile (1 MB) fetched ~once per XCD L2.
__global__ __launch_bounds__(256) void gemm2_db(
    const unsigned short* __restrict__ A,   // H1 [rows][4096]
    const unsigned short* __restrict__ Bt,  // Wt2 [E][1024][4096]
    const float* __restrict__ bias, float* __restrict__ out,
    const int* __restrict__ row_of, const float* __restrict__ s_of,
    const int* __restrict__ tile_map, const int* __restrict__ ntiles) {
  const int K = HDIM, N = DMODEL;
  const int xcd = blockIdx.x & 7;
  const int slot = blockIdx.x >> 3;  // 0..79
  const int lt = slot >> 4;          // 0..4
  const int ct = slot & 15;
  const int nt = *ntiles;
  const int q = nt >> 3, r = nt & 7;
  const int cnt = q + (xcd < r ? 1 : 0);
  if (lt >= cnt) return;
  const int tile = (xcd < r ? xcd * (q + 1) : r * (q + 1) + (xcd - r) * q) + lt;
  const int e = tile_map[tile * 4 + 0];
  const int row0 = tile_map[tile * 4 + 1];
  const int rows = tile_map[tile * 4 + 2];
  const int n0 = ct * 64;
  const unsigned short* B_e = Bt + (long)e * N * K + (long)n0 * K;

  __shared__ __align__(16) unsigned short Asm[2][BM * BK];
  __shared__ __align__(16) unsigned short Bsm[2][64 * BK];

  const int tid = threadIdx.x;
  const int lane = tid & 63;
  const int w = tid >> 6;
  const int wr = w * 32;
  const int l15 = lane & 15;
  const int l4 = lane >> 4;
  const int rA = tid >> 3, kcA = tid & 7;

  f32x4 acc[2][4] = {};

#define STAGE2D(buf, k0)                                                      \
  {                                                                           \
    _Pragma("unroll") for (int it = 0; it < 4; ++it) {                        \
      int rr = it * 32 + rA;                                                  \
      int kcs = kcA ^ (rr & 7);                                               \
      load_lds16(A + (size_t)(row0 + rr) * K + (k0) + kcs * 8,                \
                 ((char*)Asm[buf]) + (size_t)(it * 256 + w * 64) * 16);       \
    }                                                                         \
    _Pragma("unroll") for (int it = 0; it < 2; ++it) {                        \
      int rr = it * 32 + rA;                                                  \
      int kcs = kcA ^ (rr & 7);                                               \
      load_lds16(B_e + (size_t)rr * K + (k0) + kcs * 8,                       \
                 ((char*)Bsm[buf]) + (size_t)(it * 256 + w * 64) * 16);       \
    }                                                                         \
  }

#define COMPUTE2D(buf)                                                        \
  {                                                                           \
    _Pragma("unroll") for (int kk = 0; kk < 2; ++kk) {                        \
      bf16x8 a[2], b[4];                                                      \
      _Pragma("unroll") for (int m = 0; m < 2; ++m) {                         \
        int row = wr + m * 16 + l15;                                          \
        int ch = (kk * 4 + l4) ^ (l15 & 7);                                   \
        a[m] = *(const bf16x8*)&Asm[buf][row * BK + ch * 8];                  \
      }                                                                       \
      _Pragma("unroll") for (int n = 0; n < 4; ++n) {                         \
        int row = n * 16 + l15;                                               \
        int ch = (kk * 4 + l4) ^ (l15 & 7);                                   \
        b[n] = *(const bf16x8*)&Bsm[buf][row * BK + ch * 8];                  \
      }                                                                       \
      _Pragma("unroll") for (int m = 0; m < 2; ++m)                           \
          _Pragma("unroll") for (int n = 0; n < 4; ++n) acc[m][n] =           \
              __builtin_amdgcn_mfma_f32_16x16x32_bf16(a[m], b[n], acc[m][n],  \
                                                      0, 0, 0);               \
    }                                                                         \
  }

  const int nsteps = K / BK;  // 64
  STAGE2D(0, 0);
  STAGE2D(1, BK);
#pragma unroll 1
  for (int t = 0; t < nsteps - 1; ++t) {
    asm volatile("s_waitcnt vmcnt(6)" ::: "memory");
    __builtin_amdgcn_s_barrier();
    COMPUTE2D(t & 1);
    __builtin_amdgcn_s_barrier();
    if (t + 2 < nsteps) STAGE2D(t & 1, (t + 2) * BK);
  }
  asm volatile("s_waitcnt vmcnt(0)" ::: "memory");
  __builtin_amdgcn_s_barrier();
  COMPUTE2D((nsteps - 1) & 1);
#undef STAGE2D
#undef COMPUTE2D

  const float* bias_e = bias + (long)e * DMODEL;
#pragma unroll
  for (int m = 0; m < 2; ++m) {
#pragma unroll
    for (int i = 0; i < 4; ++i) {
      int rr = wr + m * 16 + l4 * 4 + i;
      if (rr < rows) {
        int tok = row_of[row0 + rr];
        float s = s_of[row0 + rr];
        float* op = out + (size_t)tok * DMODEL;
#pragma unroll
        for (int n = 0; n < 4; ++n) {
          int cg = n0 + n * 16 + l15;
          float v = acc[m][n][i] + bias_e[cg];
          atomicAdd(&op[cg], s * v);
        }
      }
    }
  }
}

extern "C" void kernel_launch(void* const* d_in, const int* in_sizes, int n_in,
                              void* d_out, int out_size, void* d_ws, size_t ws_size,
                              hipStream_t stream) {
  const float* x = (const float*)d_in[0];
  const float* gw = (const float*)d_in[1];
  const float* gb = (const float*)d_in[2];
  const float* w1 = (const float*)d_in[3];
  const float* b1 = (const float*)d_in[4];
  const float* w2 = (const float*)d_in[5];
  const float* b2 = (const float*)d_in[6];
  float* out = (float*)d_out;
  char* ws = (char*)d_ws;

  int* ntiles = (int*)(ws + 128);
  int* nt256 = (int*)(ws + 132);
  int* tile_map = (int*)(ws + 256);
  int* tm256 = (int*)(ws + 2048);
  int* idx2 = (int*)(ws + 4096);
  float* sc2 = (float*)(ws + 20480);
  int* pos_of = (int*)(ws + 36864);
  int* row_of = (int*)(ws + 53248);   // 4352 ints (256-entry tail guard)
  float* s_of = (float*)(ws + 73728);
  unsigned short* x16 = (unsigned short*)(ws + 131072);   // 2048x1024 bf16
  unsigned short* H1 = (unsigned short*)(ws + 8781824);   // 4224x4096 bf16
  unsigned short* Wt1 = (unsigned short*)(ws + 43384832); // 8x4096x1024 bf16
  unsigned short* Wt2 = (unsigned short*)(ws + 110493696);// 8x1024x4096 bf16
  if (ws_size < 110493696ULL) return;
  const bool fused2 = ws_size >= 177602560ULL;

  // [gate | conv1] fused: 512 gate blocks + 8192 conv1 blocks
  gate_conv_kernel<<<512 + NEXP * (DMODEL / 64) * (HDIM / 64), 256, 0, stream>>>(
      x, gw, gb, idx2, sc2, out, x16, w1, Wt1);
  route_kernel<<<1, 256, 0, stream>>>(idx2, sc2, tile_map, ntiles, tm256, nt256,
                                      pos_of, row_of, s_of);
  if (fused2) {
    // [G1 | conv2] fused: conv2 -> separate Wt2 buffer (no race with G1's Wt1)
    g1conv2_kernel<<<NG1 + 4096, 512, 0, stream>>>(
        x16, row_of, Wt1, b1, H1, tm256, nt256, w2, Wt2);
    gemm2_db<<<8 * 80, 256, 0, stream>>>(H1, Wt2, b2, out, row_of, s_of,
                                         tile_map, ntiles);
  } else {
    // fallback: serial G1 then conv2 into Wt1 region (round-14 order)
    g1conv2_kernel<<<NG1, 512, 0, stream>>>(x16, row_of, Wt1, b1, H1, tm256,
                                            nt256, w2, Wt1);
    convT_kernel<<<NEXP * (HDIM / 64) * (DMODEL / 64), 256, 0, stream>>>(
        w2, Wt1, HDIM, DMODEL, DMODEL / 64, NEXP * (HDIM / 64) * (DMODEL / 64) / 8);
    gemm2_db<<<8 * 80, 256, 0, stream>>>(H1, Wt1, b2, out, row_of, s_of,
                                         tile_map, ntiles);
  }
}

// Round 17
// 234.006 us; speedup vs baseline: 1.0501x; 1.0501x over previous
//
#include <hip/hip_runtime.h>
#include <math.h>

#define B_TOK 2048
#define DMODEL 1024
#define HDIM 4096
#define NEXP 8
#define TOPK 2

#define BM 128
#define BK 64
#define MAX_TILES 40
#define MAX_T256 24
#define NG1 768  // MAX_T256 * (HDIM/128); divisible by 8

typedef __attribute__((ext_vector_type(8))) short bf16x8;
typedef __attribute__((ext_vector_type(4))) float f32x4;

__device__ __forceinline__ unsigned short f2b(float f) {
  unsigned u = __builtin_bit_cast(unsigned, f);
  unsigned r = (u + 0x7FFFu + ((u >> 16) & 1u)) >> 16;
  return (unsigned short)r;
}

__device__ __forceinline__ void load_lds16(const void* g, void* l) {
  __builtin_amdgcn_global_load_lds(
      (const __attribute__((address_space(1))) unsigned int*)g,
      (__attribute__((address_space(3))) unsigned int*)l, 16, 0, 0);
}

// exact-gelu via branchless A&S 7.1.26 erf (|err| <= 1.5e-7, << bf16 ulp)
__device__ __forceinline__ float gelu_fast(float v) {
  float x = v * 0.70710678118654752f;
  float ax = fabsf(x);
  float t = 1.0f / (1.0f + 0.3275911f * ax);
  float e = exp2f(-ax * ax * 1.4426950408889634f);
  float p = t * (0.254829592f +
                 t * (-0.284496736f +
                      t * (1.421413741f +
                           t * (-1.453152027f + t * 1.061405429f))));
  float er = 1.0f - p * e;
  er = copysignf(er, x);
  return 0.5f * v * (1.0f + er);
}

// ---- fused [gate | conv1]: blocks 0..511 gate (+x16 convert, +out zero),
// ---- blocks 512.. conv1 (w1 [E][D][H] f32 -> Wt1 [E][H][D] bf16).
__global__ __launch_bounds__(256) void gate_conv_kernel(
    const float* __restrict__ x, const float* __restrict__ gw,
    const float* __restrict__ gb, int* __restrict__ idx2,
    float* __restrict__ sc2, float* __restrict__ out,
    unsigned short* __restrict__ x16, const float* __restrict__ W,
    unsigned short* __restrict__ Wt) {
  __shared__ unsigned L[64 * 33];
  if (blockIdx.x < 512) {
    int lane = threadIdx.x & 63;
    int w = threadIdx.x >> 6;
    int b = blockIdx.x * 4 + w;
    {
      float4 z = make_float4(0.f, 0.f, 0.f, 0.f);
      float* orow = out + (size_t)(blockIdx.x * 4) * DMODEL;
#pragma unroll
      for (int i = 0; i < 4; ++i)
        *(float4*)(orow + i * 1024 + threadIdx.x * 4) = z;
    }
    double acc[NEXP];
#pragma unroll
    for (int e = 0; e < NEXP; ++e) acc[e] = 0.0;
    const float* xr = x + (size_t)b * DMODEL;
#pragma unroll
    for (int i = 0; i < 4; ++i) {
      float4 xv = *(const float4*)(xr + i * 256 + lane * 4);
      ushort4 o = make_ushort4(f2b(xv.x), f2b(xv.y), f2b(xv.z), f2b(xv.w));
      *(ushort4*)(x16 + (size_t)b * DMODEL + i * 256 + lane * 4) = o;
#pragma unroll
      for (int e = 0; e < NEXP; ++e) {
        float4 wv = *(const float4*)(gw + e * DMODEL + i * 256 + lane * 4);
        acc[e] += (double)xv.x * wv.x + (double)xv.y * wv.y +
                  (double)xv.z * wv.z + (double)xv.w * wv.w;
      }
    }
#pragma unroll
    for (int e = 0; e < NEXP; ++e) {
      double v = acc[e];
      for (int o = 1; o < 64; o <<= 1) v += __shfl_xor(v, o, 64);
      acc[e] = v + (double)gb[e];
    }
    if (lane == 0) {
      int i0 = 0;
      double v0 = acc[0];
#pragma unroll
      for (int e = 1; e < NEXP; ++e)
        if (acc[e] > v0) { v0 = acc[e]; i0 = e; }
      int i1 = -1;
      double v1 = -1e300;
#pragma unroll
      for (int e = 0; e < NEXP; ++e)
        if (e != i0 && acc[e] > v1) { v1 = acc[e]; i1 = e; }
      double t = exp(v1 - v0);
      float s0 = (float)(1.0 / (1.0 + t));
      float s1 = (float)(t / (1.0 + t));
      idx2[b * 2] = i0;
      idx2[b * 2 + 1] = i1;
      sc2[b * 2] = s0;
      sc2[b * 2 + 1] = s1;
    }
  } else {
    int bid0 = blockIdx.x - 512;
    int bidx = (bid0 & 7) * 1024 + (bid0 >> 3);
    int nt = bidx % (HDIM / 64);
    int r2 = bidx / (HDIM / 64);
    int kt = r2 % (DMODEL / 64);
    int e = r2 / (DMODEL / 64);
    int tid = threadIdx.x;

    const float* src =
        W + (long)e * DMODEL * HDIM + (long)(kt * 64) * HDIM + nt * 64;
    int kp = tid >> 3;
    int nb = tid & 7;
    const float* r0 = src + (long)(2 * kp) * HDIM + nb * 8;
    const float* r1 = r0 + HDIM;
    float4 va0 = *(const float4*)r0;
    float4 va1 = *(const float4*)(r0 + 4);
    float4 vb0 = *(const float4*)r1;
    float4 vb1 = *(const float4*)(r1 + 4);
    const float* a = (const float*)&va0;
    const float* bq = (const float*)&vb0;
#pragma unroll
    for (int j = 0; j < 4; ++j) {
      unsigned p = (unsigned)f2b(a[j]) | ((unsigned)f2b(bq[j]) << 16);
      L[(nb * 8 + j) * 33 + kp] = p;
    }
    const float* a2 = (const float*)&va1;
    const float* b2 = (const float*)&vb1;
#pragma unroll
    for (int j = 0; j < 4; ++j) {
      unsigned p = (unsigned)f2b(a2[j]) | ((unsigned)f2b(b2[j]) << 16);
      L[(nb * 8 + 4 + j) * 33 + kp] = p;
    }
    __syncthreads();
    int n = tid >> 2;
    int part = tid & 3;
    unsigned q[8];
#pragma unroll
    for (int j = 0; j < 8; ++j) q[j] = L[n * 33 + part * 8 + j];
    unsigned* dst = (unsigned*)(Wt + (long)e * HDIM * DMODEL +
                                (long)(nt * 64 + n) * DMODEL + kt * 64) +
                    part * 8;
    *(uint4*)dst = make_uint4(q[0], q[1], q[2], q[3]);
    *(uint4*)(dst + 4) = make_uint4(q[4], q[5], q[6], q[7]);
  }
}

// ---- route: single block; histogram + stable counting sort + BOTH tile maps ----
__global__ __launch_bounds__(256) void route_kernel(
    const int* __restrict__ idx2, const float* __restrict__ sc2,
    int* __restrict__ tile_map, int* __restrict__ ntiles,
    int* __restrict__ tm256, int* __restrict__ nt256,
    int* __restrict__ pos_of, int* __restrict__ row_of,
    float* __restrict__ s_of) {
  __shared__ int lc[NEXP][257];
  __shared__ int offs[NEXP + 1];
  const int tid = threadIdx.x;
  const int base = tid * 16;
  row_of[4096 + tid] = 0;  // tail guard for G1's indirect staging
#pragma unroll
  for (int e = 0; e < NEXP; ++e) lc[e][tid + 1] = 0;
  if (tid < NEXP) lc[tid][0] = 0;
  __syncthreads();
  int loc[16];
#pragma unroll
  for (int j = 0; j < 16; ++j) {
    int e = idx2[base + j];
    loc[j] = e;
    atomicAdd(&lc[e][tid + 1], 1);
  }
  __syncthreads();
  if (tid < NEXP) {
    int s = 0;
    for (int i = 1; i <= 256; ++i) {
      s += lc[tid][i];
      lc[tid][i] = s;
    }
  }
  __syncthreads();
  if (tid == 0) {
    offs[0] = 0;
    for (int e = 0; e < NEXP; ++e) offs[e + 1] = offs[e] + lc[e][256];
    int tt = 0, t2 = 0;
    for (int e = 0; e < NEXP; ++e) {
      int cnt = lc[e][256];
      int bse = offs[e];
      for (int t = 0; t * BM < cnt; ++t) {
        tile_map[tt * 4 + 0] = e;
        tile_map[tt * 4 + 1] = bse + t * BM;
        tile_map[tt * 4 + 2] = (cnt - t * BM) < BM ? (cnt - t * BM) : BM;
        tile_map[tt * 4 + 3] = 0;
        ++tt;
      }
      for (int t = 0; t * 256 < cnt; ++t) {
        tm256[t2 * 4 + 0] = e;
        tm256[t2 * 4 + 1] = bse + t * 256;
        tm256[t2 * 4 + 2] = (cnt - t * 256) < 256 ? (cnt - t * 256) : 256;
        tm256[t2 * 4 + 3] = 0;
        ++t2;
      }
    }
    *ntiles = tt;
    *nt256 = t2;
  }
  __syncthreads();
#pragma unroll
  for (int e = 0; e < NEXP; ++e) lc[e][tid] += offs[e];
  __syncthreads();
#pragma unroll
  for (int j = 0; j < 16; ++j) {
    int e = loc[j];
    int p = lc[e][tid];
    lc[e][tid] = p + 1;
    int t = base + j;
    pos_of[t] = p;
    row_of[p] = t >> 1;
    s_of[p] = sc2[t];
  }
}

// ---- standalone conv2 (fallback path): W[e][k][n] f32 -> Wt[e][n][k] bf16 ----
__global__ __launch_bounds__(256) void convT_kernel(
    const float* __restrict__ W, unsigned short* __restrict__ Wt, int Kd, int Nd,
    int tilesN, int cpx) {
  __shared__ unsigned L[64 * 33];
  int bidx = (blockIdx.x & 7) * cpx + (blockIdx.x >> 3);
  int nt = bidx % tilesN;
  int r2 = bidx / tilesN;
  int tilesK = Kd >> 6;
  int kt = r2 % tilesK;
  int e = r2 / tilesK;
  int tid = threadIdx.x;

  const float* src = W + (long)e * Kd * Nd + (long)(kt * 64) * Nd + nt * 64;
  int kp = tid >> 3;
  int nb = tid & 7;
  const float* r0 = src + (long)(2 * kp) * Nd + nb * 8;
  const float* r1 = r0 + Nd;
  float4 va0 = *(const float4*)r0;
  float4 va1 = *(const float4*)(r0 + 4);
  float4 vb0 = *(const float4*)r1;
  float4 vb1 = *(const float4*)(r1 + 4);
  const float* a = (const float*)&va0;
  const float* bq = (const float*)&vb0;
#pragma unroll
  for (int j = 0; j < 4; ++j) {
    unsigned p = (unsigned)f2b(a[j]) | ((unsigned)f2b(bq[j]) << 16);
    L[(nb * 8 + j) * 33 + kp] = p;
  }
  const float* a2 = (const float*)&va1;
  const float* b2 = (const float*)&vb1;
#pragma unroll
  for (int j = 0; j < 4; ++j) {
    unsigned p = (unsigned)f2b(a2[j]) | ((unsigned)f2b(b2[j]) << 16);
    L[(nb * 8 + 4 + j) * 33 + kp] = p;
  }
  __syncthreads();
  int n = tid >> 2;
  int part = tid & 3;
  unsigned q[8];
#pragma unroll
  for (int j = 0; j < 8; ++j) q[j] = L[n * 33 + part * 8 + j];
  unsigned* dst = (unsigned*)(Wt + (long)e * Nd * Kd + (long)(nt * 64 + n) * Kd +
                              kt * 64) +
                  part * 8;
  *(uint4*)dst = make_uint4(q[0], q[1], q[2], q[3]);
  *(uint4*)(dst + 4) = make_uint4(q[4], q[5], q[6], q[7]);
}

// ---- fused [G1 | conv2]: blocks <NG1 = G1 (256x128, 512 thr, proven body);
// ---- blocks >=NG1 = conv2 (w2 f32 -> Wt2 bf16), 2 tiles per 512-thr block.
__global__ __launch_bounds__(512) void g1conv2_kernel(
    const unsigned short* __restrict__ x16, const int* __restrict__ row_of,
    const unsigned short* __restrict__ Bt, const float* __restrict__ bias,
    unsigned short* __restrict__ Cout, const int* __restrict__ tm256,
    const int* __restrict__ nt256, const float* __restrict__ W2,
    unsigned short* __restrict__ Wt2) {
  __shared__ __align__(16) char SM[49152];
  if (blockIdx.x < NG1) {
    const int K = DMODEL, N = HDIM;
    const int nb = N / 128;
    const int tile = blockIdx.x / nb;
    if (tile >= *nt256) return;
    const int ct = blockIdx.x % nb;
    const int e = tm256[tile * 4 + 0];
    const int row0 = tm256[tile * 4 + 1];
    const int rows = tm256[tile * 4 + 2];
    const int n0 = ct * 128;
    const unsigned short* B_e = Bt + (long)e * (long)N * K + (long)n0 * K;

    unsigned short* Asm = (unsigned short*)SM;            // 256*64
    unsigned short* Bsm = (unsigned short*)SM + 256 * BK; // 128*64

    const int tid = threadIdx.x;
    const int lane = tid & 63;
    const int w = tid >> 6;
    const int wr = (w >> 1) * 64;
    const int wc = (w & 1) * 64;
    const int l15 = lane & 15;
    const int l4 = lane >> 4;

    int gr[4];
#pragma unroll
    for (int it = 0; it < 4; ++it) gr[it] = row_of[row0 + it * 64 + (tid >> 3)];
    const int kcsA = (tid & 7) ^ ((tid >> 3) & 7);

    f32x4 acc[4][4] = {};

    for (int k0 = 0; k0 < K; k0 += BK) {
#pragma unroll
      for (int it = 0; it < 4; ++it) {
        load_lds16(x16 + (size_t)gr[it] * K + k0 + kcsA * 8,
                   ((char*)Asm) + (size_t)(it * 512 + w * 64) * 16);
      }
#pragma unroll
      for (int it = 0; it < 2; ++it) {
        int c = it * 512 + tid;
        int r = c >> 3, kc = c & 7;
        int kcs = kc ^ (r & 7);
        load_lds16(B_e + (size_t)r * K + k0 + kcs * 8,
                   ((char*)Bsm) + (size_t)(it * 512 + w * 64) * 16);
      }
      __syncthreads();
#pragma unroll
      for (int kk = 0; kk < 2; ++kk) {
        bf16x8 a[4], b[4];
#pragma unroll
        for (int m = 0; m < 4; ++m) {
          int row = wr + m * 16 + l15;
          int ch = (kk * 4 + l4) ^ (l15 & 7);
          a[m] = *(const bf16x8*)&Asm[row * BK + ch * 8];
        }
#pragma unroll
        for (int n = 0; n < 4; ++n) {
          int row = wc + n * 16 + l15;
          int ch = (kk * 4 + l4) ^ (l15 & 7);
          b[n] = *(const bf16x8*)&Bsm[row * BK + ch * 8];
        }
#pragma unroll
        for (int m = 0; m < 4; ++m)
#pragma unroll
          for (int n = 0; n < 4; ++n)
            acc[m][n] = __builtin_amdgcn_mfma_f32_16x16x32_bf16(a[m], b[n],
                                                                acc[m][n], 0, 0, 0);
      }
      __syncthreads();
    }

    const float* bias_e = bias + (long)e * HDIM;
#pragma unroll
    for (int m = 0; m < 4; ++m) {
#pragma unroll
      for (int i = 0; i < 4; ++i) {
        int r = wr + m * 16 + l4 * 4 + i;
        if (r < rows) {
          size_t grow = (size_t)(row0 + r) * HDIM;
#pragma unroll
          for (int n = 0; n < 4; ++n) {
            int cg = n0 + wc + n * 16 + l15;
            float v = acc[m][n][i] + bias_e[cg];
            v = gelu_fast(v);
            Cout[grow + cg] = f2b(v);
          }
        }
      }
    }
  } else {
    // conv2: 2 tiles per block. Kd=4096, Nd=1024, tilesN=16, 8192 tiles total.
    int lb = blockIdx.x - NG1;  // 0..4095
    int half = threadIdx.x >> 8;
    int tid = threadIdx.x & 255;
    int v = (lb & 7) * 1024 + (lb >> 3) + half * 512;  // XCD-chunked, bijective
    int nt = v % (DMODEL / 64);
    int r2 = v / (DMODEL / 64);
    int kt = r2 % (HDIM / 64);
    int e = r2 / (HDIM / 64);

    unsigned* L = (unsigned*)SM + half * 2112;  // 64*33 words per half

    const float* src =
        W2 + (long)e * HDIM * DMODEL + (long)(kt * 64) * DMODEL + nt * 64;
    int kp = tid >> 3;
    int nb = tid & 7;
    const float* r0 = src + (long)(2 * kp) * DMODEL + nb * 8;
    const float* r1 = r0 + DMODEL;
    float4 va0 = *(const float4*)r0;
    float4 va1 = *(const float4*)(r0 + 4);
    float4 vb0 = *(const float4*)r1;
    float4 vb1 = *(const float4*)(r1 + 4);
    const float* a = (const float*)&va0;
    const float* bq = (const float*)&vb0;
#pragma unroll
    for (int j = 0; j < 4; ++j) {
      unsigned p = (unsigned)f2b(a[j]) | ((unsigned)f2b(bq[j]) << 16);
      L[(nb * 8 + j) * 33 + kp] = p;
    }
    const float* a2 = (const float*)&va1;
    const float* b2 = (const float*)&vb1;
#pragma unroll
    for (int j = 0; j < 4; ++j) {
      unsigned p = (unsigned)f2b(a2[j]) | ((unsigned)f2b(b2[j]) << 16);
      L[(nb * 8 + 4 + j) * 33 + kp] = p;
    }
    __syncthreads();
    int n = tid >> 2;
    int part = tid & 3;
    unsigned q[8];
#pragma unroll
    for (int j = 0; j < 8; ++j) q[j] = L[n * 33 + part * 8 + j];
    unsigned* dst = (unsigned*)(Wt2 + (long)e * DMODEL * HDIM +
                                (long)(nt * 64 + n) * HDIM + kt * 64) +
                    part * 8;
    *(uint4*)dst = make_uint4(q[0], q[1], q[2], q[3]);
    *(uint4*)(dst + 4) = make_uint4(q[4], q[5], q[6], q[7]);
  }
}

// ------- G2: 128x64, double-buffered + counted vmcnt (round-12, proven) -------
__global__ __launch_bounds__(256) void gemm2_db(
    const unsigned short* __restrict__ A,   // H1 [rows][4096]
    const unsigned short* __restrict__ Bt,  // Wt2 [E][1024][4096]
    const float* __restrict__ bias, float* __restrict__ out,
    const int* __restrict__ row_of, const float* __restrict__ s_of,
    const int* __restrict__ tile_map, const int* __restrict__ ntiles) {
  const int K = HDIM, N = DMODEL;
  const int nb = N / 64;
  const int tile = blockIdx.x / nb;
  if (tile >= *ntiles) return;
  const int ct = blockIdx.x % nb;
  const int e = tile_map[tile * 4 + 0];
  const int row0 = tile_map[tile * 4 + 1];
  const int rows = tile_map[tile * 4 + 2];
  const int n0 = ct * 64;
  const unsigned short* B_e = Bt + (long)e * N * K + (long)n0 * K;

  __shared__ __align__(16) unsigned short Asm[2][BM * BK];
  __shared__ __align__(16) unsigned short Bsm[2][64 * BK];

  const int tid = threadIdx.x;
  const int lane = tid & 63;
  const int w = tid >> 6;
  const int wr = w * 32;
  const int l15 = lane & 15;
  const int l4 = lane >> 4;
  const int rA = tid >> 3, kcA = tid & 7;

  f32x4 acc[2][4] = {};

#define STAGE2D(buf, k0)                                                      \
  {                                                                           \
    _Pragma("unroll") for (int it = 0; it < 4; ++it) {                        \
      int r = it * 32 + rA;                                                   \
      int kcs = kcA ^ (r & 7);                                                \
      load_lds16(A + (size_t)(row0 + r) * K + (k0) + kcs * 8,                 \
                 ((char*)Asm[buf]) + (size_t)(it * 256 + w * 64) * 16);       \
    }                                                                         \
    _Pragma("unroll") for (int it = 0; it < 2; ++it) {                        \
      int r = it * 32 + rA;                                                   \
      int kcs = kcA ^ (r & 7);                                                \
      load_lds16(B_e + (size_t)r * K + (k0) + kcs * 8,                        \
                 ((char*)Bsm[buf]) + (size_t)(it * 256 + w * 64) * 16);       \
    }                                                                         \
  }

#define COMPUTE2D(buf)                                                        \
  {                                                                           \
    _Pragma("unroll") for (int kk = 0; kk < 2; ++kk) {                        \
      bf16x8 a[2], b[4];                                                      \
      _Pragma("unroll") for (int m = 0; m < 2; ++m) {                         \
        int row = wr + m * 16 + l15;                                          \
        int ch = (kk * 4 + l4) ^ (l15 & 7);                                   \
        a[m] = *(const bf16x8*)&Asm[buf][row * BK + ch * 8];                  \
      }                                                                       \
      _Pragma("unroll") for (int n = 0; n < 4; ++n) {                         \
        int row = n * 16 + l15;                                               \
        int ch = (kk * 4 + l4) ^ (l15 & 7);                                   \
        b[n] = *(const bf16x8*)&Bsm[buf][row * BK + ch * 8];                  \
      }                                                                       \
      _Pragma("unroll") for (int m = 0; m < 2; ++m)                           \
          _Pragma("unroll") for (int n = 0; n < 4; ++n) acc[m][n] =           \
              __builtin_amdgcn_mfma_f32_16x16x32_bf16(a[m], b[n], acc[m][n],  \
                                                      0, 0, 0);               \
    }                                                                         \
  }

  const int nsteps = K / BK;  // 64
  STAGE2D(0, 0);
  STAGE2D(1, BK);
#pragma unroll 1
  for (int t = 0; t < nsteps - 1; ++t) {
    asm volatile("s_waitcnt vmcnt(6)" ::: "memory");
    __builtin_amdgcn_s_barrier();
    COMPUTE2D(t & 1);
    __builtin_amdgcn_s_barrier();
    if (t + 2 < nsteps) STAGE2D(t & 1, (t + 2) * BK);
  }
  asm volatile("s_waitcnt vmcnt(0)" ::: "memory");
  __builtin_amdgcn_s_barrier();
  COMPUTE2D((nsteps - 1) & 1);
#undef STAGE2D
#undef COMPUTE2D

  const float* bias_e = bias + (long)e * DMODEL;
#pragma unroll
  for (int m = 0; m < 2; ++m) {
#pragma unroll
    for (int i = 0; i < 4; ++i) {
      int r = wr + m * 16 + l4 * 4 + i;
      if (r < rows) {
        int tok = row_of[row0 + r];
        float s = s_of[row0 + r];
        float* op = out + (size_t)tok * DMODEL;
#pragma unroll
        for (int n = 0; n < 4; ++n) {
          int cg = n0 + n * 16 + l15;
          float v = acc[m][n][i] + bias_e[cg];
          atomicAdd(&op[cg], s * v);
        }
      }
    }
  }
}

extern "C" void kernel_launch(void* const* d_in, const int* in_sizes, int n_in,
                              void* d_out, int out_size, void* d_ws, size_t ws_size,
                              hipStream_t stream) {
  const float* x = (const float*)d_in[0];
  const float* gw = (const float*)d_in[1];
  const float* gb = (const float*)d_in[2];
  const float* w1 = (const float*)d_in[3];
  const float* b1 = (const float*)d_in[4];
  const float* w2 = (const float*)d_in[5];
  const float* b2 = (const float*)d_in[6];
  float* out = (float*)d_out;
  char* ws = (char*)d_ws;

  int* ntiles = (int*)(ws + 128);
  int* nt256 = (int*)(ws + 132);
  int* tile_map = (int*)(ws + 256);
  int* tm256 = (int*)(ws + 2048);
  int* idx2 = (int*)(ws + 4096);
  float* sc2 = (float*)(ws + 20480);
  int* pos_of = (int*)(ws + 36864);
  int* row_of = (int*)(ws + 53248);   // 4352 ints (256-entry tail guard)
  float* s_of = (float*)(ws + 73728);
  unsigned short* x16 = (unsigned short*)(ws + 131072);   // 2048x1024 bf16
  unsigned short* H1 = (unsigned short*)(ws + 8781824);   // 4224x4096 bf16
  unsigned short* Wt1 = (unsigned short*)(ws + 43384832); // 8x4096x1024 bf16
  unsigned short* Wt2 = (unsigned short*)(ws + 110493696);// 8x1024x4096 bf16
  if (ws_size < 110493696ULL) return;
  const bool fused2 = ws_size >= 177602560ULL;

  // [gate | conv1] fused: 512 gate blocks + 8192 conv1 blocks
  gate_conv_kernel<<<512 + NEXP * (DMODEL / 64) * (HDIM / 64), 256, 0, stream>>>(
      x, gw, gb, idx2, sc2, out, x16, w1, Wt1);
  route_kernel<<<1, 256, 0, stream>>>(idx2, sc2, tile_map, ntiles, tm256, nt256,
                                      pos_of, row_of, s_of);
  if (fused2) {
    // [G1 | conv2] fused: conv2 -> separate Wt2 buffer (no race with G1's Wt1)
    g1conv2_kernel<<<NG1 + 4096, 512, 0, stream>>>(
        x16, row_of, Wt1, b1, H1, tm256, nt256, w2, Wt2);
    gemm2_db<<<MAX_TILES * (DMODEL / 64), 256, 0, stream>>>(
        H1, Wt2, b2, out, row_of, s_of, tile_map, ntiles);
  } else {
    // fallback: serial G1 then conv2 into Wt1 region (round-14 order)
    g1conv2_kernel<<<NG1, 512, 0, stream>>>(x16, row_of, Wt1, b1, H1, tm256,
                                            nt256, w2, Wt1);
    convT_kernel<<<NEXP * (HDIM / 64) * (DMODEL / 64), 256, 0, stream>>>(
        w2, Wt1, HDIM, DMODEL, DMODEL / 64, NEXP * (HDIM / 64) * (DMODEL / 64) / 8);
    gemm2_db<<<MAX_TILES * (DMODEL / 64), 256, 0, stream>>>(
        H1, Wt1, b2, out, row_of, s_of, tile_map, ntiles);
  }
}